// Round 7
// baseline (224.625 us; speedup 1.0000x reference)
//
#include <hip/hip_runtime.h>

#define DIM 128      // feature dim, fixed per reference
#define HBD 64       // dst-histogram blocks (rank capture)
#define HBS 64       // src-histogram blocks (out-degree)
#define HWORDS 25088 // max padded (N+1)/2 supported by LDS histogram (100,352 B)
#define WSTR 136     // LDS stride for W tiles (bf16 elems): 16B aligned

typedef __attribute__((ext_vector_type(8))) short b8;            // 8 bf16 (4 VGPRs)
typedef __attribute__((ext_vector_type(4))) float f4;            // MFMA acc
typedef __attribute__((ext_vector_type(8))) unsigned short u16x8; // 16B bf16 chunk

// bf16 helpers: RNE float->bf16, exact bf16->float
static __device__ __forceinline__ unsigned short f2bf(float f) {
    unsigned u = __float_as_uint(f);
    u += 0x7fffu + ((u >> 16) & 1u);
    return (unsigned short)(u >> 16);
}
static __device__ __forceinline__ float bf2f(unsigned short b) {
    return __uint_as_float((unsigned)b << 16);
}

// ---------------- split LDS histograms + W prep + flag zero ----------------
// Blocks [0,HBD): dst (in-degree) histogram with per-edge rank capture.
// Blocks [HBD,HBD+HBS): src (out-degree) histogram.
// Blocks [HBD+HBS,+2): W1/W2 hi/lo transpose prep; first zeroes scan flags.
// 1024 thr/block (4 waves/SIMD) hides load+LDS-atomic latency (round-3 win).
// NO cast here (cast needs norm_src; R5/R6 showed hiding it under hist nets ~0).
// NO global atomics (round-1 lesson: 600k device-scope atomics cost ~20us).
__global__ __launch_bounds__(1024) void k_hist(const int* __restrict__ src,
                                               const int* __restrict__ dst,
                                               unsigned short* __restrict__ local,
                                               unsigned* __restrict__ hist_in,
                                               unsigned* __restrict__ hist_out,
                                               const float* __restrict__ W1,
                                               const float* __restrict__ W2,
                                               unsigned short* __restrict__ w1hi,
                                               unsigned short* __restrict__ w1lo,
                                               unsigned short* __restrict__ w2hi,
                                               unsigned short* __restrict__ w2lo,
                                               int* __restrict__ scan_aux,
                                               int E, int W2p, int slice_d, int slice_s) {
    const int t = threadIdx.x;
    const int bx = blockIdx.x;
    if (bx < HBD + HBS) {
        __shared__ unsigned h[HWORDS];
        const bool is_dst = bx < HBD;            // block-uniform
        const int b = is_dst ? bx : bx - HBD;
        const int slice = is_dst ? slice_d : slice_s;
        const int e0 = b * slice;
        const int e1 = min(e0 + slice, E);
        const int W4 = W2p >> 2;
        uint4* h4 = (uint4*)h;

        for (int w = t; w < W4; w += 1024) h4[w] = make_uint4(0u, 0u, 0u, 0u);
        __syncthreads();

        if (is_dst) {
            int e = e0 + t;
            int d = (e < e1) ? dst[e] : 0;
            while (e < e1) {
                int en = e + 1024;
                int dn = (en < e1) ? dst[en] : 0;   // prefetch next iter's index
                unsigned sh = (unsigned)(d & 1) * 16u;
                unsigned old = atomicAdd(&h[d >> 1], 1u << sh);
                local[e] = (unsigned short)((old >> sh) & 0xffffu);
                e = en; d = dn;
            }
        } else {
            int e = e0 + t;
            int s = (e < e1) ? src[e] : 0;
            while (e < e1) {
                int en = e + 1024;
                int sn = (en < e1) ? src[en] : 0;
                atomicAdd(&h[s >> 1], 1u << ((unsigned)(s & 1) * 16u));
                e = en; s = sn;
            }
        }
        __syncthreads();

        uint4* o = (uint4*)((is_dst ? hist_in : hist_out) + (size_t)b * W2p);
        for (int w = t; w < W4; w += 1024) o[w] = h4[w];
    } else {
        int b = bx - (HBD + HBS);
        if (b == 0 && t < 256) scan_aux[t] = 0;   // zero lookback flags (ws re-poisoned!)
        const float* W = b ? W2 : W1;
        unsigned short* Hi = b ? w2hi : w1hi;
        unsigned short* Lo = b ? w2lo : w1lo;
        for (int e = t; e < DIM * DIM; e += 1024) {
            int k = e >> 7, c = e & 127;
            float w = W[e];
            unsigned short hi = f2bf(w);
            unsigned short lo = f2bf(w - bf2f(hi));
            Hi[c * DIM + k] = hi;
            Lo[c * DIM + k] = lo;
        }
    }
}

// ---------------- fused column scan + node prefix + norms (decoupled lookback) --------
// One block per 256 packed words (512 nodes); <=98 blocks, all co-resident on 256 CUs,
// so the spin-wait lookback cannot deadlock. Everything stays in registers; emits
// row_off + both norms directly.
// NOTE: do NOT fuse k_fillcast into this kernel — row_off/hist_in prefixes are plain
// stores; cross-XCD L2 visibility within one kernel is not guaranteed (G16).
__global__ __launch_bounds__(256) void k_scan(unsigned* __restrict__ hist_in,
                                              const unsigned* __restrict__ hist_out,
                                              int* __restrict__ partials,   // scan_aux[0..)
                                              int* __restrict__ flags,      // scan_aux[128..)
                                              int* __restrict__ row_off,
                                              float* __restrict__ norm_src,
                                              float* __restrict__ norm_dst,
                                              int W2, int W2p, int N) {
    __shared__ int wsum[4];
    __shared__ int wbase[4];
    __shared__ int psum[4];
    __shared__ int base_s;
    const int t = threadIdx.x;
    const int b = blockIdx.x;
    const int w = b * 256 + t;
    const int lane = t & 63, wave = t >> 6;

    unsigned run = 0, run2 = 0;
    if (w < W2) {
        unsigned* p = hist_in + w;
        #pragma unroll 8
        for (int i = 0; i < HBD; ++i) {
            unsigned x = *p;
            *p = run;          // exclusive packed prefix over blocks (for k_fillcast)
            run += x;          // halves independent (each < 65536)
            p += W2p;
        }
        const unsigned* q = hist_out + w;
        #pragma unroll 8
        for (int i = 0; i < HBS; ++i) { run2 += *q; q += W2p; }
    }
    const int n0 = w * 2, n1 = n0 + 1;
    const int lo = (int)(run & 0xffffu), hi = (int)(run >> 16);
    const int s = (w < W2) ? (lo + ((n1 < N) ? hi : 0)) : 0;

    // wave-inclusive scan of per-thread node sums
    int x = s;
    #pragma unroll
    for (int off = 1; off < 64; off <<= 1) {
        int y = __shfl_up(x, off, 64);
        if (lane >= off) x += y;
    }
    if (lane == 63) wsum[wave] = x;
    __syncthreads();
    if (t == 0) {
        int acc = 0;
        #pragma unroll
        for (int i = 0; i < 4; ++i) { int v = wsum[i]; wbase[i] = acc; acc += v; }
        partials[b] = acc;                 // publish block total
        __threadfence();                   // release
        atomicExch(&flags[b], 1);
    }
    __syncthreads();

    // lookback: thread t waits on block t (< b); b <= 97 < 256 so one thread per block
    int pre = 0;
    if (t < b) {
        while (atomicAdd(&flags[t], 0) == 0) { __builtin_amdgcn_s_sleep(2); }
        pre = atomicAdd(&partials[t], 0);  // coherent read
    }
    #pragma unroll
    for (int off = 32; off > 0; off >>= 1) pre += __shfl_down(pre, off, 64);
    if (lane == 0) psum[wave] = pre;
    __syncthreads();
    if (t == 0) base_s = psum[0] + psum[1] + psum[2] + psum[3];
    __syncthreads();
    const int B = base_s;

    if (w < W2) {
        int tb = B + wbase[wave] + (x - s);   // exclusive offset of node n0
        row_off[n0] = tb;
        int dlo = lo < 1 ? 1 : lo;
        norm_dst[n0] = rsqrtf((float)dlo);
        int o0 = (int)(run2 & 0xffffu); if (o0 < 1) o0 = 1;
        norm_src[n0] = rsqrtf((float)o0);
        if (n1 < N) {
            row_off[n1] = tb + lo;
            int dhi = hi < 1 ? 1 : hi;
            norm_dst[n1] = rsqrtf((float)dhi);
            int o1 = (int)(run2 >> 16); if (o1 < 1) o1 = 1;
            norm_src[n1] = rsqrtf((float)o1);
            if (n1 == N - 1) row_off[N] = tb + lo + hi;
        } else if (n0 == N - 1) {
            row_off[N] = tb + lo;
        }
    }
}

// ---------------- fused: atomic-free CSR fill + SCALED feature cast ----------------
// blocks [0,eb): edge scatter; [eb,eb+cb): fp32->bf16 cast of feat*norm_src (single
// rounding — R3 numerics; norms ready since this runs after k_scan). Cast rides the
// CUs the tiny edge blocks free up. Both spmms then need ZERO norm loads.
__global__ __launch_bounds__(256) void k_fillcast(
        const int* __restrict__ src, const int* __restrict__ dst,
        const int* __restrict__ row_off,
        const unsigned short* __restrict__ local,
        const unsigned* __restrict__ hist_in,
        int* __restrict__ csr_src,
        const float* __restrict__ feat, const float* __restrict__ norm_src,
        unsigned short* __restrict__ fbf,
        int E, int W2p, int slice, int eb, int n4) {
    int bx = blockIdx.x;
    if (bx < eb) {
        int e = bx * 256 + threadIdx.x;
        if (e < E) {
            int d = dst[e];
            int b = e / slice;
            unsigned sh = (unsigned)(d & 1) * 16u;
            unsigned bo = (hist_in[(size_t)b * W2p + (d >> 1)] >> sh) & 0xffffu;
            csr_src[row_off[d] + (int)bo + (int)local[e]] = src[e];
        }
    } else {
        int i = (bx - eb) * 256 + threadIdx.x;
        if (i < n4) {
            float4 v = ((const float4*)feat)[i];
            float ns = norm_src[i >> 5];   // 32 float4 per node row
            ushort4 o;
            o.x = f2bf(v.x * ns); o.y = f2bf(v.y * ns);
            o.z = f2bf(v.z * ns); o.w = f2bf(v.w * ns);
            ((ushort4*)fbf)[i] = o;
        }
    }
}

// ---------------- fallback edge pass (global atomics) for oversized N ----------------
__global__ __launch_bounds__(256) void k_edge_pass_fb(const int* __restrict__ src,
                                                      const int* __restrict__ dst,
                                                      int* __restrict__ deg_out,
                                                      int* __restrict__ cnt,
                                                      int* __restrict__ local_fb, int E) {
    int e = blockIdx.x * 256 + threadIdx.x;
    if (e < E) {
        atomicAdd(&deg_out[src[e]], 1);
        local_fb[e] = atomicAdd(&cnt[dst[e]], 1);
    }
}

// ---------------- fallback block-reduce ----------------
__global__ __launch_bounds__(256) void k_block_reduce(const int* __restrict__ deg,
                                                      int* __restrict__ bsum, int N) {
    __shared__ int wsum[4];
    int i = blockIdx.x * 256 + threadIdx.x;
    int x = (i < N) ? deg[i] : 0;
    #pragma unroll
    for (int off = 32; off > 0; off >>= 1) x += __shfl_down(x, off, 64);
    int lane = threadIdx.x & 63, wave = threadIdx.x >> 6;
    if (lane == 0) wsum[wave] = x;
    __syncthreads();
    if (threadIdx.x == 0) bsum[blockIdx.x] = wsum[0] + wsum[1] + wsum[2] + wsum[3];
}

// ---------------- fallback scan_final with inline block-prefix ----------------
__global__ __launch_bounds__(256) void k_scan_final(const int* __restrict__ cnt,
                                                    const int* __restrict__ deg_out,
                                                    const int* __restrict__ bsum,
                                                    int* __restrict__ row_off,
                                                    float* __restrict__ norm_src,
                                                    float* __restrict__ norm_dst, int N) {
    __shared__ int wsum[4];
    __shared__ int base_s;
    const int t = threadIdx.x;
    const int lane = t & 63, wave = t >> 6;

    int pre = 0;
    for (int i = t; i < blockIdx.x; i += 256) pre += bsum[i];
    #pragma unroll
    for (int off = 32; off > 0; off >>= 1) pre += __shfl_down(pre, off, 64);
    if (lane == 0) wsum[wave] = pre;
    __syncthreads();
    if (t == 0) base_s = wsum[0] + wsum[1] + wsum[2] + wsum[3];
    __syncthreads();
    const int bpre_v = base_s;

    int i = blockIdx.x * 256 + t;
    int x = (i < N) ? cnt[i] : 0;
    int orig = x;
    #pragma unroll
    for (int off = 1; off < 64; off <<= 1) {
        int y = __shfl_up(x, off, 64);
        if (lane >= off) x += y;
    }
    if (lane == 63) wsum[wave] = x;
    __syncthreads();
    if (t == 0) {
        int s = 0;
        for (int w = 0; w < 4; ++w) { int tt = wsum[w]; wsum[w] = s; s += tt; }
    }
    __syncthreads();
    x += wsum[wave] + bpre_v;
    if (i < N) {
        row_off[i] = x - orig;
        int di = orig < 1 ? 1 : orig;
        norm_dst[i] = rsqrtf((float)di);
        int dov = deg_out[i]; if (dov < 1) dov = 1;
        norm_src[i] = rsqrtf((float)dov);
    }
    if (i == N - 1) row_off[N] = x;
}

// ---------------- fallback: CSR fill + scaled cast + weight prep ----------
__global__ __launch_bounds__(256) void k_fill_cast_prep_fb(
        const int* __restrict__ src, const int* __restrict__ dst,
        const int* __restrict__ row_off,
        const int* __restrict__ local_fb,
        int* __restrict__ csr_src,
        const float* __restrict__ feat, const float* __restrict__ norm_src,
        unsigned short* __restrict__ fbf,
        const float* __restrict__ W1, const float* __restrict__ W2,
        unsigned short* __restrict__ w1hi, unsigned short* __restrict__ w1lo,
        unsigned short* __restrict__ w2hi, unsigned short* __restrict__ w2lo,
        int E, int eb, int cb, int pb, int n4) {
    int bx = blockIdx.x;
    if (bx < eb) {
        int e = bx * 256 + threadIdx.x;
        if (e < E) {
            int d = dst[e];
            csr_src[row_off[d] + local_fb[e]] = src[e];
        }
    } else if (bx < eb + cb) {
        int i = (bx - eb) * 256 + threadIdx.x;
        if (i < n4) {
            float4 v = ((const float4*)feat)[i];
            float ns = norm_src[i >> 5];
            ushort4 o;
            o.x = f2bf(v.x * ns); o.y = f2bf(v.y * ns);
            o.z = f2bf(v.z * ns); o.w = f2bf(v.w * ns);
            ((ushort4*)fbf)[i] = o;
        }
    } else {
        int b = bx - eb - cb;
        const float* W; unsigned short *Hi, *Lo;
        if (b < pb) { W = W1; Hi = w1hi; Lo = w1lo; } else { W = W2; Hi = w2hi; Lo = w2lo; b -= pb; }
        int e = b * 256 + threadIdx.x;
        if (e < DIM * DIM) {
            int k = e >> 7, c = e & 127;
            float w = W[e];
            unsigned short hi = f2bf(w);
            unsigned short lo = f2bf(w - bf2f(hi));
            Hi[c * DIM + k] = hi;
            Lo[c * DIM + k] = lo;
        }
    }
}

// ---------------- CSR SpMM over pre-scaled bf16 rows -> bf16 agg ----------------
// agg[d] = norm_dst[d] * sum_{s in in(d)} row(s) [* norm_src[s] if SCALE]
// 16 lanes per node, u16x8 (16B) per lane -> 256B/row; 4 nodes/wave; index prefetch
// one quad ahead. Launched SCALE=false on both layers (inputs pre-scaled).
template<bool SCALE>
__global__ __launch_bounds__(256) void k_spmm(const unsigned short* __restrict__ hb,
                                              const int* __restrict__ csr_src,
                                              const int* __restrict__ row_off,
                                              const float* __restrict__ norm_src,
                                              const float* __restrict__ norm_dst,
                                              unsigned short* __restrict__ aggbf, int N) {
    int t = blockIdx.x * 256 + threadIdx.x;
    int node = t >> 4;
    int lane = t & 15;
    if (node >= N) return;
    int beg = row_off[node], end = row_off[node + 1];
    float a0[8] = {0.f, 0.f, 0.f, 0.f, 0.f, 0.f, 0.f, 0.f};
    float a1[8] = {0.f, 0.f, 0.f, 0.f, 0.f, 0.f, 0.f, 0.f};
    int i = beg;
    int s0 = 0, s1 = 0, s2 = 0, s3 = 0;
    if (i + 4 <= end) {
        s0 = csr_src[i]; s1 = csr_src[i + 1]; s2 = csr_src[i + 2]; s3 = csr_src[i + 3];
    }
    while (i + 4 <= end) {
        u16x8 u0 = *((const u16x8*)(hb + (size_t)s0 * DIM) + lane);
        u16x8 u1 = *((const u16x8*)(hb + (size_t)s1 * DIM) + lane);
        u16x8 u2 = *((const u16x8*)(hb + (size_t)s2 * DIM) + lane);
        u16x8 u3 = *((const u16x8*)(hb + (size_t)s3 * DIM) + lane);
        float ns0 = 1.f, ns1 = 1.f, ns2 = 1.f, ns3 = 1.f;
        if (SCALE) {
            ns0 = norm_src[s0]; ns1 = norm_src[s1];
            ns2 = norm_src[s2]; ns3 = norm_src[s3];
        }
        int i2 = i + 4;
        if (i2 + 4 <= end) {   // prefetch next quad's indices (exec-masked per node)
            s0 = csr_src[i2]; s1 = csr_src[i2 + 1]; s2 = csr_src[i2 + 2]; s3 = csr_src[i2 + 3];
        }
        #pragma unroll
        for (int j = 0; j < 8; ++j) {
            if (SCALE) {
                a0[j] = fmaf(bf2f(u0[j]), ns0, a0[j]);
                a1[j] = fmaf(bf2f(u1[j]), ns1, a1[j]);
                a0[j] = fmaf(bf2f(u2[j]), ns2, a0[j]);
                a1[j] = fmaf(bf2f(u3[j]), ns3, a1[j]);
            } else {
                a0[j] += bf2f(u0[j]);
                a1[j] += bf2f(u1[j]);
                a0[j] += bf2f(u2[j]);
                a1[j] += bf2f(u3[j]);
            }
        }
        i = i2;
    }
    for (; i < end; ++i) {
        int s = csr_src[i];
        float ns = SCALE ? norm_src[s] : 1.f;
        u16x8 u = *((const u16x8*)(hb + (size_t)s * DIM) + lane);
        #pragma unroll
        for (int j = 0; j < 8; ++j) {
            if (SCALE) a0[j] = fmaf(bf2f(u[j]), ns, a0[j]);
            else       a0[j] += bf2f(u[j]);
        }
    }
    float nd = norm_dst[node];
    u16x8 o;
    #pragma unroll
    for (int j = 0; j < 8; ++j) o[j] = f2bf((a0[j] + a1[j]) * nd);
    *((u16x8*)(aggbf + (size_t)node * DIM) + lane) = o;
}

// ---------------- MFMA GEMM: out = [ps ⊙] relu(Abf @ (Whi+Wlo) + b) ----------------
// postscale (norm_src) in gemm1's epilogue pre-scales h1bf so spmm2 needs no norm loads.
__global__ __launch_bounds__(256, 2) void k_gemm_mfma(
        const unsigned short* __restrict__ A,      // [N][128] bf16
        const unsigned short* __restrict__ Wt_hi,  // [c][k] bf16
        const unsigned short* __restrict__ Wt_lo,
        const float* __restrict__ bias,
        const float* __restrict__ postscale,       // null => none
        float* __restrict__ outf, unsigned short* __restrict__ outbf, int N) {
    __shared__ unsigned short WH[DIM * WSTR];
    __shared__ unsigned short WL[DIM * WSTR];

    const int t = threadIdx.x;
    #pragma unroll
    for (int i = 0; i < 8; ++i) {
        int e = (t + i * 256) * 8;      // elem idx in [c][k] 128x128
        int c = e >> 7, k = e & 127;
        *(float4*)(WH + c * WSTR + k) = *(const float4*)(Wt_hi + e);
        *(float4*)(WL + c * WSTR + k) = *(const float4*)(Wt_lo + e);
    }
    __syncthreads();

    const int wv = t >> 6;
    const int l = t & 63;
    const int m = l & 15;
    const int quad = l >> 4;
    const int row_t0 = blockIdx.x * 128 + wv * 32;

    f4 acc[2][8];
    #pragma unroll
    for (int rt = 0; rt < 2; ++rt)
        #pragma unroll
        for (int ct = 0; ct < 8; ++ct)
            acc[rt][ct] = (f4){0.f, 0.f, 0.f, 0.f};

    int r0 = row_t0 + m;      if (r0 >= N) r0 = N - 1;   // clamp; stores guarded
    int r1 = row_t0 + 16 + m; if (r1 >= N) r1 = N - 1;

    #pragma unroll
    for (int ks = 0; ks < 4; ++ks) {
        int koff = ks * 32 + quad * 8;
        b8 a0 = *(const b8*)(A + (size_t)r0 * DIM + koff);
        b8 a1 = *(const b8*)(A + (size_t)r1 * DIM + koff);
        #pragma unroll
        for (int ct = 0; ct < 8; ++ct) {
            int c = ct * 16 + m;
            b8 bh = *(const b8*)(WH + c * WSTR + koff);
            b8 bl = *(const b8*)(WL + c * WSTR + koff);
            acc[0][ct] = __builtin_amdgcn_mfma_f32_16x16x32_bf16(a0, bh, acc[0][ct], 0, 0, 0);
            acc[0][ct] = __builtin_amdgcn_mfma_f32_16x16x32_bf16(a0, bl, acc[0][ct], 0, 0, 0);
            acc[1][ct] = __builtin_amdgcn_mfma_f32_16x16x32_bf16(a1, bh, acc[1][ct], 0, 0, 0);
            acc[1][ct] = __builtin_amdgcn_mfma_f32_16x16x32_bf16(a1, bl, acc[1][ct], 0, 0, 0);
        }
    }

    #pragma unroll
    for (int rt = 0; rt < 2; ++rt) {
        int rowb = row_t0 + rt * 16 + quad * 4;
        #pragma unroll
        for (int r = 0; r < 4; ++r) {
            int gr = rowb + r;
            if (gr < N) {
                float s = postscale ? postscale[gr] : 1.f;
                #pragma unroll
                for (int ct = 0; ct < 8; ++ct) {
                    int col = ct * 16 + m;
                    float v = fmaxf(acc[rt][ct][r] + bias[col], 0.f) * s;
                    if (outbf) outbf[(size_t)gr * DIM + col] = f2bf(v);
                    else       outf[(size_t)gr * DIM + col] = v;
                }
            }
        }
    }
}

static inline size_t align_up(size_t x, size_t a) { return (x + a - 1) & ~(a - 1); }

extern "C" void kernel_launch(void* const* d_in, const int* in_sizes, int n_in,
                              void* d_out, int out_size, void* d_ws, size_t ws_size,
                              hipStream_t stream) {
    const float* features = (const float*)d_in[0];
    const int*   src      = (const int*)d_in[1];
    const int*   dst      = (const int*)d_in[2];
    const float* W1       = (const float*)d_in[3];
    const float* b1       = (const float*)d_in[4];
    const float* W2       = (const float*)d_in[5];
    const float* b2       = (const float*)d_in[6];
    float* out = (float*)d_out;

    const int N = in_sizes[0] / DIM;
    const int E = in_sizes[1];
    const int B = (N + 255) / 256;
    const int W2w = (N + 1) >> 1;                 // packed histogram words
    const int W2p = (W2w + 3) & ~3;               // padded row stride (16B-aligned rows)
    const int slice_d = (E + HBD - 1) / HBD;
    const int slice_s = (E + HBS - 1) / HBS;
    const int cs_blocks = (W2w + 255) / 256;      // <= 98 on fast path (all co-resident)

    // workspace carve-up
    size_t nodeb = align_up((size_t)N * 4, 256);
    char* p = (char*)d_ws;
    int*   deg_out  = (int*)p;                      p += nodeb;   // fallback only
    int*   cnt      = (int*)p;                      p += nodeb;   // fallback only
    float* norm_src = (float*)p;                    p += nodeb;
    float* norm_dst = (float*)p;                    p += nodeb;
    int*   row_off  = (int*)p;                      p += align_up((size_t)(N + 1) * 4, 256);
    int*   scan_aux = (int*)p;                      p += align_up((size_t)(B + 256) * 4, 256);
    int*   csr_src  = (int*)p;                      p += align_up((size_t)E * 4, 256);
    char*  big      = p;                            p += 2 * (size_t)N * DIM * 4;  // 51.2 MB region
    unsigned short* w1hi = (unsigned short*)p;      p += (size_t)DIM * DIM * 2;
    unsigned short* w1lo = (unsigned short*)p;      p += (size_t)DIM * DIM * 2;
    unsigned short* w2hi = (unsigned short*)p;      p += (size_t)DIM * DIM * 2;
    unsigned short* w2lo = (unsigned short*)p;      p += (size_t)DIM * DIM * 2;
    // steady-state layout inside big:
    unsigned short* aggbf = (unsigned short*)big;                           // [0, 12.8 MB)
    unsigned short* h1bf  = (unsigned short*)(big + (size_t)N * DIM * 2);   // [12.8, 25.6)
    unsigned short* fbf   = (unsigned short*)(big + 3 * (size_t)N * DIM * 2); // [38.4, 51.2)
    // graph-build aliases over big[0, ~14 MB) — disjoint from fbf; overwritten by
    // aggbf/h1bf only after k_fillcast is done with them (serial stream):
    char* ap = big;
    unsigned short* local = (unsigned short*)ap;    ap += align_up((size_t)E * 2, 256);
    unsigned* hist_in  = (unsigned*)ap;             ap += (size_t)HBD * W2p * 4;
    unsigned* hist_out = (unsigned*)ap;             ap += (size_t)HBS * W2p * 4;
    int* local_fb = (int*)big;                      // fallback path only
    int* partials = scan_aux;                       // [0, cs_blocks)
    int* flags    = scan_aux + 128;                 // [128, 128+cs_blocks), zeroed by k_hist
    int* bsum     = scan_aux;                       // fallback reuse (B <= B+256 carve)

    const int edge_blocks = (E + 255) / 256;
    const int spmm_blocks = (int)(((size_t)N * 16 + 255) / 256);
    const int gemm_blocks = (N + 127) / 128;
    const int n4 = N * (DIM / 4);
    const int cast_blocks = (n4 + 255) / 256;

    // fast path requires: padded histogram fits LDS; lookback co-residency (<=256 blocks);
    // graph aliases fit below fbf
    const bool fast = (W2p <= HWORDS) && (cs_blocks <= 256) &&
        (align_up((size_t)E * 2, 256) + (size_t)(HBD + HBS) * W2p * 4
            <= 3 * (size_t)N * DIM * 2);

    if (fast) {
        k_hist<<<HBD + HBS + 2, 1024, 0, stream>>>(src, dst, local, hist_in, hist_out,
                                                   W1, W2, w1hi, w1lo, w2hi, w2lo,
                                                   scan_aux, E, W2p, slice_d, slice_s);
        k_scan<<<cs_blocks, 256, 0, stream>>>(hist_in, hist_out, partials, flags,
                                              row_off, norm_src, norm_dst, W2w, W2p, N);
        k_fillcast<<<edge_blocks + cast_blocks, 256, 0, stream>>>(
            src, dst, row_off, local, hist_in, csr_src,
            features, norm_src, fbf, E, W2p, slice_d, edge_blocks, n4);
    } else {
        const int prep_blocks = (DIM * DIM + 255) / 256;
        hipMemsetAsync(deg_out, 0, nodeb * 2, stream);
        k_edge_pass_fb<<<edge_blocks, 256, 0, stream>>>(src, dst, deg_out, cnt, local_fb, E);
        k_block_reduce<<<B, 256, 0, stream>>>(cnt, bsum, N);
        k_scan_final<<<B, 256, 0, stream>>>(cnt, deg_out, bsum, row_off, norm_src, norm_dst, N);
        k_fill_cast_prep_fb<<<edge_blocks + cast_blocks + 2 * prep_blocks, 256, 0, stream>>>(
            src, dst, row_off, local_fb, csr_src, features, norm_src, fbf,
            W1, W2, w1hi, w1lo, w2hi, w2lo,
            E, edge_blocks, cast_blocks, prep_blocks, n4);
    }

    // layer 1: gather pre-scaled fbf (no norm loads) -> aggbf; GEMM W1 (+postscale
    // norm_src in epilogue pre-scales h1 for layer 2) -> h1bf
    k_spmm<false><<<spmm_blocks, 256, 0, stream>>>(fbf, csr_src, row_off,
                                                   (const float*)nullptr,
                                                   norm_dst, aggbf, N);
    k_gemm_mfma<<<gemm_blocks, 256, 0, stream>>>(aggbf, w1hi, w1lo, b1, norm_src,
                                                 (float*)nullptr, h1bf, N);

    // layer 2: gather pre-scaled h1 (no norm loads) -> aggbf; GEMM W2 -> out (fp32)
    k_spmm<false><<<spmm_blocks, 256, 0, stream>>>(h1bf, csr_src, row_off,
                                                   (const float*)nullptr,
                                                   norm_dst, aggbf, N);
    k_gemm_mfma<<<gemm_blocks, 256, 0, stream>>>(aggbf, w2hi, w2lo, b2,
                                                 (const float*)nullptr,
                                                 out, (unsigned short*)nullptr, N);
}

// Round 8
// 206.576 us; speedup vs baseline: 1.0874x; 1.0874x over previous
//
#include <hip/hip_runtime.h>

#define DIM 128      // feature dim, fixed per reference
#define HBD 64       // dst-histogram blocks (rank capture)
#define HBS 64       // src-histogram blocks (out-degree)
#define HWORDS 25088 // max padded (N+1)/2 supported by LDS histogram (100,352 B)
#define WSTR 136     // LDS stride for W tiles (bf16 elems): 16B aligned, 2-way banks

typedef __attribute__((ext_vector_type(8))) short b8;            // 8 bf16 (4 VGPRs)
typedef __attribute__((ext_vector_type(4))) float f4;            // MFMA acc
typedef __attribute__((ext_vector_type(8))) unsigned short u16x8; // 16B bf16 chunk

// bf16 helpers: RNE float->bf16, exact bf16->float
static __device__ __forceinline__ unsigned short f2bf(float f) {
    unsigned u = __float_as_uint(f);
    u += 0x7fffu + ((u >> 16) & 1u);
    return (unsigned short)(u >> 16);
}
static __device__ __forceinline__ float bf2f(unsigned short b) {
    return __uint_as_float((unsigned)b << 16);
}

// ---------------- LDS-privatized histogram, split src/dst blocks ----------------
// EXACT round-3 anchor (208.1 us session best). Rounds 4-7 structural variants all
// regressed (R4 +6, R5 +6, R6 +8, R7 +14 controllable-normalized); this resubmission
// re-validates the anchor and measures harness reproducibility.
// Blocks [0,HBD): dst (in-degree) histogram with per-edge rank capture.
// Blocks [HBD,HBD+HBS): src (out-degree) histogram.
// 1024 threads/block: 4 waves/SIMD hides the dst-load + LDS-atomic latency chain;
// 1-deep prefetch issues next edge's load a full iteration early.
// NO global atomics (round-1 lesson: 600k device-scope atomics cost ~20us).
__global__ __launch_bounds__(1024) void k_hist(const int* __restrict__ src,
                                               const int* __restrict__ dst,
                                               unsigned short* __restrict__ local,
                                               unsigned* __restrict__ hist_in,
                                               unsigned* __restrict__ hist_out,
                                               int E, int W2p, int slice_d, int slice_s) {
    __shared__ unsigned h[HWORDS];
    const int t = threadIdx.x;
    const bool is_dst = blockIdx.x < HBD;            // block-uniform
    const int b = is_dst ? blockIdx.x : blockIdx.x - HBD;
    const int slice = is_dst ? slice_d : slice_s;
    const int e0 = b * slice;
    const int e1 = min(e0 + slice, E);
    const int W4 = W2p >> 2;
    uint4* h4 = (uint4*)h;

    for (int w = t; w < W4; w += 1024) h4[w] = make_uint4(0u, 0u, 0u, 0u);
    __syncthreads();

    if (is_dst) {
        int e = e0 + t;
        int d = (e < e1) ? dst[e] : 0;
        while (e < e1) {
            int en = e + 1024;
            int dn = (en < e1) ? dst[en] : 0;   // prefetch next iter's index
            unsigned sh = (unsigned)(d & 1) * 16u;
            unsigned old = atomicAdd(&h[d >> 1], 1u << sh);
            local[e] = (unsigned short)((old >> sh) & 0xffffu);
            e = en; d = dn;
        }
    } else {
        int e = e0 + t;
        int s = (e < e1) ? src[e] : 0;
        while (e < e1) {
            int en = e + 1024;
            int sn = (en < e1) ? src[en] : 0;
            atomicAdd(&h[s >> 1], 1u << ((unsigned)(s & 1) * 16u));
            e = en; s = sn;
        }
    }
    __syncthreads();

    uint4* o = (uint4*)((is_dst ? hist_in : hist_out) + (size_t)b * W2p);
    for (int w = t; w < W4; w += 1024) o[w] = h4[w];
}

// ---------------- flat column scan over histogram copies + fused block-reduce ----------------
// Thread w scans its packed word across the HBD in-histogram copies (exclusive prefix
// written back for the fill kernel) and sums the HBS out-histogram copies; emits total
// in-degree (cnt), out-degree (deg_out), and per-256-node partial sums (bsum).
__global__ __launch_bounds__(256) void k_colscan(unsigned* __restrict__ hist_in,
                                                 const unsigned* __restrict__ hist_out,
                                                 int* __restrict__ cnt,
                                                 int* __restrict__ deg_out,
                                                 int* __restrict__ bsum,
                                                 int W2, int W2p, int N) {
    __shared__ int wsum[4];
    int w = blockIdx.x * 256 + threadIdx.x;
    unsigned run = 0;
    if (w < W2) {
        unsigned* p = hist_in + w;
        #pragma unroll 8
        for (int b = 0; b < HBD; ++b) {
            unsigned x = *p;
            *p = run;          // exclusive packed prefix over blocks
            run += x;          // halves independent (each < 65536)
            p += W2p;
        }
        unsigned run2 = 0;
        const unsigned* q = hist_out + w;
        #pragma unroll 8
        for (int b = 0; b < HBS; ++b) { run2 += *q; q += W2p; }
        int n0 = w * 2;
        if (n0 + 1 < N) {
            *(int2*)(cnt + n0)     = make_int2((int)(run & 0xffffu), (int)(run >> 16));
            *(int2*)(deg_out + n0) = make_int2((int)(run2 & 0xffffu), (int)(run2 >> 16));
        } else {
            cnt[n0]     = (int)(run & 0xffffu);
            deg_out[n0] = (int)(run2 & 0xffffu);
            run &= 0xffffu;    // exclude phantom high half from bsum
        }
    }
    int tot = (int)(run & 0xffffu) + (int)(run >> 16);
    #pragma unroll
    for (int off = 32; off > 0; off >>= 1) tot += __shfl_down(tot, off, 64);
    int lane = threadIdx.x & 63, wave = threadIdx.x >> 6;
    if (lane == 0) wsum[wave] = tot;
    __syncthreads();
    if (threadIdx.x == 0)   bsum[2 * blockIdx.x]     = wsum[0] + wsum[1];
    if (threadIdx.x == 128) bsum[2 * blockIdx.x + 1] = wsum[2] + wsum[3];
}

// ---------------- fallback edge pass (global atomics) for oversized N ----------------
__global__ __launch_bounds__(256) void k_edge_pass_fb(const int* __restrict__ src,
                                                      const int* __restrict__ dst,
                                                      int* __restrict__ deg_out,
                                                      int* __restrict__ cnt,
                                                      int* __restrict__ local_fb, int E) {
    int e = blockIdx.x * 256 + threadIdx.x;
    if (e < E) {
        atomicAdd(&deg_out[src[e]], 1);
        local_fb[e] = atomicAdd(&cnt[dst[e]], 1);
    }
}

// ---------------- fallback block-reduce ----------------
__global__ __launch_bounds__(256) void k_block_reduce(const int* __restrict__ deg,
                                                      int* __restrict__ bsum, int N) {
    __shared__ int wsum[4];
    int i = blockIdx.x * 256 + threadIdx.x;
    int x = (i < N) ? deg[i] : 0;
    #pragma unroll
    for (int off = 32; off > 0; off >>= 1) x += __shfl_down(x, off, 64);
    int lane = threadIdx.x & 63, wave = threadIdx.x >> 6;
    if (lane == 0) wsum[wave] = x;
    __syncthreads();
    if (threadIdx.x == 0) bsum[blockIdx.x] = wsum[0] + wsum[1] + wsum[2] + wsum[3];
}

// ---------------- scan_final with inline block-prefix ----------------
__global__ __launch_bounds__(256) void k_scan_final(const int* __restrict__ cnt,
                                                    const int* __restrict__ deg_out,
                                                    const int* __restrict__ bsum,
                                                    int* __restrict__ row_off,
                                                    float* __restrict__ norm_src,
                                                    float* __restrict__ norm_dst, int N) {
    __shared__ int wsum[4];
    __shared__ int base_s;
    const int t = threadIdx.x;
    const int lane = t & 63, wave = t >> 6;

    int pre = 0;
    for (int i = t; i < blockIdx.x; i += 256) pre += bsum[i];
    #pragma unroll
    for (int off = 32; off > 0; off >>= 1) pre += __shfl_down(pre, off, 64);
    if (lane == 0) wsum[wave] = pre;
    __syncthreads();
    if (t == 0) base_s = wsum[0] + wsum[1] + wsum[2] + wsum[3];
    __syncthreads();
    const int bpre_v = base_s;

    int i = blockIdx.x * 256 + t;
    int x = (i < N) ? cnt[i] : 0;
    int orig = x;
    #pragma unroll
    for (int off = 1; off < 64; off <<= 1) {
        int y = __shfl_up(x, off, 64);
        if (lane >= off) x += y;
    }
    if (lane == 63) wsum[wave] = x;
    __syncthreads();
    if (t == 0) {
        int s = 0;
        for (int w = 0; w < 4; ++w) { int tt = wsum[w]; wsum[w] = s; s += tt; }
    }
    __syncthreads();
    x += wsum[wave] + bpre_v;
    if (i < N) {
        row_off[i] = x - orig;
        int di = orig < 1 ? 1 : orig;
        norm_dst[i] = rsqrtf((float)di);
        int dov = deg_out[i]; if (dov < 1) dov = 1;
        norm_src[i] = rsqrtf((float)dov);
    }
    if (i == N - 1) row_off[N] = x;
}

// ---------------- fused: CSR fill + prescaled feature cast + weight prep ----------------
// blocks [0,eb): atomic-free scatter fill; [eb,eb+cb): fp32->bf16 cast of
// features*norm_src (norms ready: runs after k_scan_final); [eb+cb, +2*pb): W prep.
__global__ __launch_bounds__(256) void k_fill_cast_prep(
        const int* __restrict__ src, const int* __restrict__ dst,
        const int* __restrict__ row_off,
        const unsigned short* __restrict__ local,
        const int* __restrict__ local_fb,
        const unsigned* __restrict__ hist_in,
        int* __restrict__ csr_src,
        const float* __restrict__ feat, const float* __restrict__ norm_src,
        unsigned short* __restrict__ fbf,
        const float* __restrict__ W1, const float* __restrict__ W2,
        unsigned short* __restrict__ w1hi, unsigned short* __restrict__ w1lo,
        unsigned short* __restrict__ w2hi, unsigned short* __restrict__ w2lo,
        int E, int W2p, int slice, int eb, int cb, int pb, int n4) {
    int bx = blockIdx.x;
    if (bx < eb) {
        int e = bx * 256 + threadIdx.x;
        if (e < E) {
            int d = dst[e];
            int pos = row_off[d];
            if (hist_in) {
                int b = e / slice;
                unsigned sh = (unsigned)(d & 1) * 16u;
                unsigned bo = (hist_in[(size_t)b * W2p + (d >> 1)] >> sh) & 0xffffu;
                pos += (int)bo + (int)local[e];
            } else {
                pos += local_fb[e];
            }
            csr_src[pos] = src[e];
        }
    } else if (bx < eb + cb) {
        int i = (bx - eb) * 256 + threadIdx.x;
        if (i < n4) {
            float4 v = ((const float4*)feat)[i];
            float ns = norm_src[i >> 5];   // 32 float4 per node row
            ushort4 o;
            o.x = f2bf(v.x * ns); o.y = f2bf(v.y * ns);
            o.z = f2bf(v.z * ns); o.w = f2bf(v.w * ns);
            ((ushort4*)fbf)[i] = o;
        }
    } else {
        int b = bx - eb - cb;
        const float* W; unsigned short *Hi, *Lo;
        if (b < pb) { W = W1; Hi = w1hi; Lo = w1lo; } else { W = W2; Hi = w2hi; Lo = w2lo; b -= pb; }
        int e = b * 256 + threadIdx.x;
        if (e < DIM * DIM) {
            int k = e >> 7, c = e & 127;
            float w = W[e];
            unsigned short hi = f2bf(w);
            unsigned short lo = f2bf(w - bf2f(hi));
            Hi[c * DIM + k] = hi;
            Lo[c * DIM + k] = lo;
        }
    }
}

// ---------------- CSR SpMM over pre-scaled bf16 rows -> bf16 agg ----------------
// 16 lanes per node, u16x8 (8 bf16, 16B) per lane -> 256B/row; 4 nodes/wave,
// 16 outstanding gathers/wave at 4-deep unroll; fp32 accumulate; bf16 out.
__global__ __launch_bounds__(256) void k_spmm(const unsigned short* __restrict__ hb,
                                              const int* __restrict__ csr_src,
                                              const int* __restrict__ row_off,
                                              const float* __restrict__ norm_dst,
                                              unsigned short* __restrict__ aggbf, int N) {
    int t = blockIdx.x * 256 + threadIdx.x;
    int node = t >> 4;
    int lane = t & 15;
    if (node >= N) return;
    int beg = row_off[node], end = row_off[node + 1];
    float a0[8] = {0.f, 0.f, 0.f, 0.f, 0.f, 0.f, 0.f, 0.f};
    float a1[8] = {0.f, 0.f, 0.f, 0.f, 0.f, 0.f, 0.f, 0.f};
    int i = beg;
    for (; i + 4 <= end; i += 4) {
        int s0 = csr_src[i], s1 = csr_src[i + 1], s2 = csr_src[i + 2], s3 = csr_src[i + 3];
        u16x8 u0 = *((const u16x8*)(hb + (size_t)s0 * DIM) + lane);
        u16x8 u1 = *((const u16x8*)(hb + (size_t)s1 * DIM) + lane);
        u16x8 u2 = *((const u16x8*)(hb + (size_t)s2 * DIM) + lane);
        u16x8 u3 = *((const u16x8*)(hb + (size_t)s3 * DIM) + lane);
        #pragma unroll
        for (int j = 0; j < 8; ++j) {
            a0[j] += bf2f(u0[j]);
            a1[j] += bf2f(u1[j]);
            a0[j] += bf2f(u2[j]);
            a1[j] += bf2f(u3[j]);
        }
    }
    for (; i < end; ++i) {
        int s0 = csr_src[i];
        u16x8 u0 = *((const u16x8*)(hb + (size_t)s0 * DIM) + lane);
        #pragma unroll
        for (int j = 0; j < 8; ++j) a0[j] += bf2f(u0[j]);
    }
    float nd = norm_dst[node];
    u16x8 o;
    #pragma unroll
    for (int j = 0; j < 8; ++j) o[j] = f2bf((a0[j] + a1[j]) * nd);
    *((u16x8*)(aggbf + (size_t)node * DIM) + lane) = o;
}

// ---------------- MFMA GEMM: out = [ps ⊙] relu(Abf @ (Whi+Wlo) + b) ----------------
__global__ __launch_bounds__(256, 2) void k_gemm_mfma(
        const unsigned short* __restrict__ A,      // [N][128] bf16
        const unsigned short* __restrict__ Wt_hi,  // [c][k] bf16
        const unsigned short* __restrict__ Wt_lo,
        const float* __restrict__ bias,
        const float* __restrict__ postscale,       // null => none
        float* __restrict__ outf, unsigned short* __restrict__ outbf, int N) {
    __shared__ unsigned short WH[DIM * WSTR];
    __shared__ unsigned short WL[DIM * WSTR];

    const int t = threadIdx.x;
    #pragma unroll
    for (int i = 0; i < 8; ++i) {
        int e = (t + i * 256) * 8;      // elem idx in [c][k] 128x128
        int c = e >> 7, k = e & 127;
        *(float4*)(WH + c * WSTR + k) = *(const float4*)(Wt_hi + e);
        *(float4*)(WL + c * WSTR + k) = *(const float4*)(Wt_lo + e);
    }
    __syncthreads();

    const int wv = t >> 6;
    const int l = t & 63;
    const int m = l & 15;
    const int quad = l >> 4;
    const int row_t0 = blockIdx.x * 128 + wv * 32;

    f4 acc[2][8];
    #pragma unroll
    for (int rt = 0; rt < 2; ++rt)
        #pragma unroll
        for (int ct = 0; ct < 8; ++ct)
            acc[rt][ct] = (f4){0.f, 0.f, 0.f, 0.f};

    int r0 = row_t0 + m;      if (r0 >= N) r0 = N - 1;   // clamp; stores guarded
    int r1 = row_t0 + 16 + m; if (r1 >= N) r1 = N - 1;

    #pragma unroll
    for (int ks = 0; ks < 4; ++ks) {
        int koff = ks * 32 + quad * 8;
        b8 a0 = *(const b8*)(A + (size_t)r0 * DIM + koff);
        b8 a1 = *(const b8*)(A + (size_t)r1 * DIM + koff);
        #pragma unroll
        for (int ct = 0; ct < 8; ++ct) {
            int c = ct * 16 + m;
            b8 bh = *(const b8*)(WH + c * WSTR + koff);
            b8 bl = *(const b8*)(WL + c * WSTR + koff);
            acc[0][ct] = __builtin_amdgcn_mfma_f32_16x16x32_bf16(a0, bh, acc[0][ct], 0, 0, 0);
            acc[0][ct] = __builtin_amdgcn_mfma_f32_16x16x32_bf16(a0, bl, acc[0][ct], 0, 0, 0);
            acc[1][ct] = __builtin_amdgcn_mfma_f32_16x16x32_bf16(a1, bh, acc[1][ct], 0, 0, 0);
            acc[1][ct] = __builtin_amdgcn_mfma_f32_16x16x32_bf16(a1, bl, acc[1][ct], 0, 0, 0);
        }
    }

    #pragma unroll
    for (int rt = 0; rt < 2; ++rt) {
        int rowb = row_t0 + rt * 16 + quad * 4;
        #pragma unroll
        for (int r = 0; r < 4; ++r) {
            int gr = rowb + r;
            if (gr < N) {
                float s = postscale ? postscale[gr] : 1.f;
                #pragma unroll
                for (int ct = 0; ct < 8; ++ct) {
                    int col = ct * 16 + m;
                    float v = fmaxf(acc[rt][ct][r] + bias[col], 0.f) * s;
                    if (outbf) outbf[(size_t)gr * DIM + col] = f2bf(v);
                    else       outf[(size_t)gr * DIM + col] = v;
                }
            }
        }
    }
}

static inline size_t align_up(size_t x, size_t a) { return (x + a - 1) & ~(a - 1); }

extern "C" void kernel_launch(void* const* d_in, const int* in_sizes, int n_in,
                              void* d_out, int out_size, void* d_ws, size_t ws_size,
                              hipStream_t stream) {
    const float* features = (const float*)d_in[0];
    const int*   src      = (const int*)d_in[1];
    const int*   dst      = (const int*)d_in[2];
    const float* W1       = (const float*)d_in[3];
    const float* b1       = (const float*)d_in[4];
    const float* W2       = (const float*)d_in[5];
    const float* b2       = (const float*)d_in[6];
    float* out = (float*)d_out;

    const int N = in_sizes[0] / DIM;
    const int E = in_sizes[1];
    const int B = (N + 255) / 256;
    const int W2w = (N + 1) >> 1;                 // packed histogram words
    const int W2p = (W2w + 3) & ~3;               // padded row stride (16B-aligned rows)
    const int slice_d = (E + HBD - 1) / HBD;
    const int slice_s = (E + HBS - 1) / HBS;
    const int cs_blocks = (W2w + 255) / 256;

    // workspace carve-up
    size_t nodeb = align_up((size_t)N * 4, 256);
    char* p = (char*)d_ws;
    int*   deg_out  = (int*)p;                      p += nodeb;
    int*   cnt      = (int*)p;                      p += nodeb;
    float* norm_src = (float*)p;                    p += nodeb;
    float* norm_dst = (float*)p;                    p += nodeb;
    int*   row_off  = (int*)p;                      p += align_up((size_t)(N + 1) * 4, 256);
    int*   bsum     = (int*)p;                      p += align_up((size_t)(2 * cs_blocks) * 4, 256);
    int*   csr_src  = (int*)p;                      p += align_up((size_t)E * 4, 256);
    char*  big      = p;                            p += 2 * (size_t)N * DIM * 4;  // 51.2 MB region
    unsigned short* w1hi = (unsigned short*)p;      p += (size_t)DIM * DIM * 2;
    unsigned short* w1lo = (unsigned short*)p;      p += (size_t)DIM * DIM * 2;
    unsigned short* w2hi = (unsigned short*)p;      p += (size_t)DIM * DIM * 2;
    unsigned short* w2lo = (unsigned short*)p;      p += (size_t)DIM * DIM * 2;
    // steady-state layout inside big:
    unsigned short* aggbf = (unsigned short*)big;                           // [0, 12.8 MB)
    unsigned short* h1bf  = (unsigned short*)(big + (size_t)N * DIM * 2);   // [12.8, 25.6)
    unsigned short* fbf   = (unsigned short*)(big + 3 * (size_t)N * DIM * 2); // [38.4, 51.2)
    // graph-build aliases over big[0, ~38 MB) — disjoint from fbf:
    char* ap = big;
    unsigned short* local = (unsigned short*)ap;    ap += align_up((size_t)E * 2, 256);
    unsigned* hist_in  = (unsigned*)ap;             ap += (size_t)HBD * W2p * 4;
    unsigned* hist_out = (unsigned*)ap;             ap += (size_t)HBS * W2p * 4;
    int* local_fb = (int*)big;                      // fallback path only

    const int edge_blocks = (E + 255) / 256;
    const int spmm_blocks = (int)(((size_t)N * 16 + 255) / 256);
    const int gemm_blocks = (N + 127) / 128;
    const int n4 = N * (DIM / 4);
    const int cast_blocks = (n4 + 255) / 256;
    const int prep_blocks = (DIM * DIM + 255) / 256;
    const int fcp_blocks  = edge_blocks + cast_blocks + 2 * prep_blocks;

    // fast path requires: padded histogram fits LDS; graph aliases fit below fbf
    const bool fast = (W2p <= HWORDS) &&
        (align_up((size_t)E * 2, 256) + (size_t)(HBD + HBS) * W2p * 4
            <= 3 * (size_t)N * DIM * 2);

    if (fast) {
        k_hist<<<HBD + HBS, 1024, 0, stream>>>(src, dst, local, hist_in, hist_out,
                                               E, W2p, slice_d, slice_s);
        k_colscan<<<cs_blocks, 256, 0, stream>>>(hist_in, hist_out, cnt, deg_out, bsum, W2w, W2p, N);
        k_scan_final<<<B, 256, 0, stream>>>(cnt, deg_out, bsum, row_off, norm_src, norm_dst, N);
        k_fill_cast_prep<<<fcp_blocks, 256, 0, stream>>>(
            src, dst, row_off, local, (const int*)nullptr, hist_in, csr_src,
            features, norm_src, fbf, W1, W2, w1hi, w1lo, w2hi, w2lo,
            E, W2p, slice_d, edge_blocks, cast_blocks, prep_blocks, n4);
    } else {
        hipMemsetAsync(deg_out, 0, nodeb * 2, stream);
        k_edge_pass_fb<<<edge_blocks, 256, 0, stream>>>(src, dst, deg_out, cnt, local_fb, E);
        k_block_reduce<<<B, 256, 0, stream>>>(cnt, bsum, N);
        k_scan_final<<<B, 256, 0, stream>>>(cnt, deg_out, bsum, row_off, norm_src, norm_dst, N);
        k_fill_cast_prep<<<fcp_blocks, 256, 0, stream>>>(
            src, dst, row_off, (const unsigned short*)nullptr, local_fb,
            (const unsigned*)nullptr, csr_src,
            features, norm_src, fbf, W1, W2, w1hi, w1lo, w2hi, w2lo,
            E, W2p, slice_d, edge_blocks, cast_blocks, prep_blocks, n4);
    }

    // layer 1: fbf already carries norm_src; gather -> aggbf; MFMA GEMM W1 -> h1bf
    // (epilogue pre-applies norm_src for layer 2's gather)
    k_spmm<<<spmm_blocks, 256, 0, stream>>>(fbf, csr_src, row_off, norm_dst, aggbf, N);
    k_gemm_mfma<<<gemm_blocks, 256, 0, stream>>>(aggbf, w1hi, w1lo, b1, norm_src,
                                                 (float*)nullptr, h1bf, N);

    // layer 2: gather pre-scaled h1 -> aggbf; MFMA GEMM W2 -> out (fp32)
    k_spmm<<<spmm_blocks, 256, 0, stream>>>(h1bf, csr_src, row_off, norm_dst, aggbf, N);
    k_gemm_mfma<<<gemm_blocks, 256, 0, stream>>>(aggbf, w2hi, w2lo, b2, (const float*)nullptr,
                                                 out, (unsigned short*)nullptr, N);
}